// Round 1
// baseline (250.872 us; speedup 1.0000x reference)
//
#include <hip/hip_runtime.h>

// ---------- types ----------
typedef unsigned short u16;
typedef __bf16 bf16x8 __attribute__((ext_vector_type(8)));
typedef float f32x4 __attribute__((ext_vector_type(4)));
typedef float f32x16 __attribute__((ext_vector_type(16)));
typedef float float4v __attribute__((ext_vector_type(4)));
typedef unsigned short u16x8 __attribute__((ext_vector_type(8)));
typedef unsigned short u16x4 __attribute__((ext_vector_type(4)));

#define MFMA16(a, b, c) __builtin_amdgcn_mfma_f32_16x16x32_bf16(a, b, c, 0, 0, 0)
#define MFMA32(a, b, c) __builtin_amdgcn_mfma_f32_32x32x16_bf16(a, b, c, 0, 0, 0)

__device__ __forceinline__ u16 f2bf(float f) {
  union { float f; unsigned u; } v; v.f = f;
  unsigned r = v.u + 0x7fffu + ((v.u >> 16) & 1u);
  return (u16)(r >> 16);
}

// async global->LDS, 16B per lane; LDS dest must be wave-uniform base + lane*16
__device__ __forceinline__ void gload16(const void* g, void* l) {
  __builtin_amdgcn_global_load_lds(
      (__attribute__((address_space(1))) void*)g,
      (__attribute__((address_space(3))) void*)l, 16, 0, 0);
}

// ---------- problem constants ----------
// B=4, L=512, A=8, D=256 -> rows M = 16384, H = 256, N(seq) = 4096 per batch

// ---------- kernel 1: fp32 -> bf16 conversions ----------
// x (4194304), conv_w (65536), theta/phi/g_w -> wcat (196608), f_w (65536), bias cat (768 f32)
__global__ __launch_bounds__(256) void convert_k(
    const float* __restrict__ x, const float* __restrict__ cw,
    const float* __restrict__ tw, const float* __restrict__ pw,
    const float* __restrict__ gw, const float* __restrict__ fw,
    const float* __restrict__ tb, const float* __restrict__ pb,
    const float* __restrict__ gb,
    u16* __restrict__ xb, u16* __restrict__ cwb, u16* __restrict__ wcat,
    u16* __restrict__ fwb, float* __restrict__ bcat) {
  const int idx = blockIdx.x * 256 + threadIdx.x;
  const float* src;
  u16* dst;
  int off;
  if (idx < 1048576)      { src = x;  dst = xb;            off = idx; }
  else if (idx < 1064960) { src = cw; dst = cwb;           off = idx - 1048576; }
  else if (idx < 1081344) { src = tw; dst = wcat;          off = idx - 1064960; }
  else if (idx < 1097728) { src = pw; dst = wcat + 65536;  off = idx - 1081344; }
  else if (idx < 1114112) { src = gw; dst = wcat + 131072; off = idx - 1097728; }
  else if (idx < 1130496) { src = fw; dst = fwb;           off = idx - 1114112; }
  else if (idx < 1130688) {
    int j = (idx - 1130496) * 4;
#pragma unroll
    for (int i = 0; i < 4; ++i) {
      int k = j + i;
      bcat[k] = (k < 256) ? tb[k] : (k < 512) ? pb[k - 256] : gb[k - 512];
    }
    return;
  } else return;
  float4v v = *(const float4v*)(src + (size_t)off * 4);
  u16x4 o;
#pragma unroll
  for (int i = 0; i < 4; ++i) o[i] = f2bf(v[i]);
  *(u16x4*)(dst + (size_t)off * 4) = o;
}

// ---------- kernel 2: generic bf16 GEMM, C[m][n] = sum_k A[m][k]*W[n][k] + bias[n] ----------
// m97 structure: 128x128 tile, BK=64, 4 waves each 64x64 of 16x16x32 frags.
// OM=0: bf16 out. OM=1: f32 out + bias + residual (final projection).
template <int OM>
__global__ __launch_bounds__(256) void gemm_bt(
    const u16* __restrict__ A, const u16* __restrict__ W,
    const float* __restrict__ bias, void* __restrict__ Cout,
    const float* __restrict__ res, int K, int ldc) {
  __shared__ u16 As[8192];
  __shared__ u16 Bs[8192];
  const int t = threadIdx.x;
  const int lane = t & 63, w = t >> 6;
  const int brow = blockIdx.x * 128, bcol = blockIdx.y * 128;
  const int wr = (w >> 1) * 64, wc = (w & 1) * 64;
  f32x4 acc[4][4];
#pragma unroll
  for (int i = 0; i < 4; ++i)
#pragma unroll
    for (int j = 0; j < 4; ++j)
#pragma unroll
      for (int r = 0; r < 4; ++r) acc[i][j][r] = 0.0f;

  const int sr = t >> 3, sc8 = (t & 7) * 8;
  const u16* gA = A + (size_t)(brow + sr) * K + sc8;
  const u16* gW = W + (size_t)(bcol + sr) * K + sc8;

  for (int kt = 0; kt < K; kt += 64) {
#pragma unroll
    for (int c = 0; c < 4; ++c) {
      gload16(gA + (size_t)c * 32 * K + kt, &As[c * 2048 + t * 8]);
      gload16(gW + (size_t)c * 32 * K + kt, &Bs[c * 2048 + t * 8]);
    }
    __syncthreads();
#pragma unroll
    for (int kk = 0; kk < 2; ++kk) {
      const int ko = kk * 32 + (lane >> 4) * 8;
      bf16x8 af[4], bfr[4];
#pragma unroll
      for (int i = 0; i < 4; ++i)
        af[i] = *(const bf16x8*)(&As[(wr + i * 16 + (lane & 15)) * 64 + ko]);
#pragma unroll
      for (int j = 0; j < 4; ++j)
        bfr[j] = *(const bf16x8*)(&Bs[(wc + j * 16 + (lane & 15)) * 64 + ko]);
#pragma unroll
      for (int i = 0; i < 4; ++i)
#pragma unroll
        for (int j = 0; j < 4; ++j)
          acc[i][j] = MFMA16(af[i], bfr[j], acc[i][j]);
    }
    __syncthreads();
  }

  const int r0 = (lane >> 4) * 4, c0 = lane & 15;
#pragma unroll
  for (int i = 0; i < 4; ++i)
#pragma unroll
    for (int j = 0; j < 4; ++j) {
      const int col = bcol + wc + j * 16 + c0;
      const float bv = bias[col];
#pragma unroll
      for (int r = 0; r < 4; ++r) {
        const size_t o = (size_t)(brow + wr + i * 16 + r0 + r) * ldc + col;
        if (OM == 0) ((u16*)Cout)[o] = f2bf(acc[i][j][r] + bv);
        else         ((float*)Cout)[o] = acc[i][j][r] + bv + res[o];
      }
    }
}

// ---------- kernel 3: transpose g -> gT[b][k][m]  (so V B-frags are contiguous) ----------
__global__ __launch_bounds__(256) void transpose_g_k(
    const u16* __restrict__ tpg, u16* __restrict__ gT) {
  __shared__ u16 T[64][65];
  const int t = threadIdx.x;
  const int bm = (blockIdx.x & 63) * 64;
  const int bk = ((blockIdx.x >> 6) & 3) * 64;
  const int b = blockIdx.x >> 8;
  const int r = t >> 3, c8 = (t & 7) * 8;
#pragma unroll
  for (int ch = 0; ch < 2; ++ch) {
    u16x8 v = *(const u16x8*)(tpg + (size_t)(b * 4096 + bm + r + ch * 32) * 768 + 512 + bk + c8);
#pragma unroll
    for (int j = 0; j < 8; ++j) T[r + ch * 32][c8 + j] = v[j];
  }
  __syncthreads();
#pragma unroll
  for (int ch = 0; ch < 2; ++ch) {
    u16x8 o;
#pragma unroll
    for (int j = 0; j < 8; ++j) o[j] = T[c8 + j][r + ch * 32];
    *(u16x8*)(gT + (size_t)(b * 256 + bk + r + ch * 32) * 4096 + bm + c8) = o;
  }
}

// ---------- kernel 4: flash attention (no max-tracking; scores bounded ~|3|) ----------
// grid 256 = b(4) x qtile(32, 128 rows) x kvhalf(2, 2048 keys). 4 waves, 32 q-rows/wave.
// 32x32x16 MFMA. K/V double-buffered LDS, XOR-swizzled (source pre-swizzled for gload_lds).
__global__ __launch_bounds__(256, 1) void flash_kernel(
    const u16* __restrict__ tpg, const u16* __restrict__ gT,
    float* __restrict__ Zp, float* __restrict__ Lp) {
  __shared__ u16 Kl[2][64 * 256];   // phi tile, rows=kv, swizzle c16(0..31)^=(r&31)
  __shared__ u16 Vl[2][256 * 64];   // gT tile, rows=headcol, swizzle c16(0..7)^=(n&7)
  __shared__ u16 Pl[4][2048];       // per-wave P (32x64), swizzle c16(0..7)^=(r&7)

  const int t = threadIdx.x;
  const int lane = t & 63;
  const int w = t >> 6;
  const int l31 = lane & 31;
  const int hi = lane >> 5;

  const int bid = blockIdx.x;
  const int b = bid >> 6;
  const int qt = (bid & 63) >> 1;
  const int half = bid & 1;
  const int q0 = qt * 128 + w * 32;  // within batch
  const int kv0 = half * 2048;

  // Q (theta) fragments in registers: lane holds Q[l31][ (hi*8..+8) + 16*kk ]
  bf16x8 q[16];
  {
    const u16* qp = tpg + (size_t)(b * 4096 + q0 + l31) * 768 + hi * 8;
#pragma unroll
    for (int kk = 0; kk < 16; ++kk) q[kk] = *(const bf16x8*)(qp + kk * 16);
  }

  f32x16 zacc[8];
#pragma unroll
  for (int i = 0; i < 8; ++i)
#pragma unroll
    for (int j = 0; j < 16; ++j) zacc[i][j] = 0.0f;
  float ell[16];
#pragma unroll
  for (int i = 0; i < 16; ++i) ell[i] = 0.0f;

  const int ks_r = t >> 5, ks_c = t & 31;  // K staging: 8 rows/chunk
  const int vs_r = t >> 3, vs_c = t & 7;   // V staging: 32 rows/chunk

  auto stage = [&](int tile, int bi) {
    const size_t krow0 = (size_t)(b * 4096 + kv0 + tile * 64);
#pragma unroll
    for (int ch = 0; ch < 8; ++ch) {
      int r = ch * 8 + ks_r;
      int csw = (ks_c ^ (r & 31)) * 8;
      gload16(tpg + (krow0 + r) * 768 + 256 + csw, &Kl[bi][ch * 2048 + t * 8]);
    }
    const size_t vbase = (size_t)b * 256 * 4096 + kv0 + tile * 64;
#pragma unroll
    for (int ch = 0; ch < 8; ++ch) {
      int n = ch * 32 + vs_r;
      int csw = (vs_c ^ (n & 7)) * 8;
      gload16(gT + vbase + (size_t)n * 4096 + csw, &Vl[bi][ch * 2048 + t * 8]);
    }
  };

  stage(0, 0);
  __syncthreads();

  for (int tile = 0; tile < 32; ++tile) {
    const int cur = tile & 1;
    if (tile + 1 < 32) stage(tile + 1, cur ^ 1);  // prefetch overlaps compute (T3)

    // S = Q * K^T : 32q x 64kv, 4 accumulation chains for MFMA pipe fill
    f32x16 s0a, s0b, s1a, s1b;
#pragma unroll
    for (int j = 0; j < 16; ++j) { s0a[j] = 0.f; s0b[j] = 0.f; s1a[j] = 0.f; s1b[j] = 0.f; }
    const u16* kb = &Kl[cur][0];
#pragma unroll
    for (int kk = 0; kk < 16; kk += 2) {
      int cA = kk * 2 + hi, cB = (kk + 1) * 2 + hi;
      bf16x8 b0a = *(const bf16x8*)(kb + l31 * 256 + ((cA ^ l31) * 8));
      bf16x8 b1a = *(const bf16x8*)(kb + (32 + l31) * 256 + ((cA ^ l31) * 8));
      bf16x8 b0b = *(const bf16x8*)(kb + l31 * 256 + ((cB ^ l31) * 8));
      bf16x8 b1b = *(const bf16x8*)(kb + (32 + l31) * 256 + ((cB ^ l31) * 8));
      s0a = MFMA32(q[kk], b0a, s0a);
      s1a = MFMA32(q[kk], b1a, s1a);
      s0b = MFMA32(q[kk + 1], b0b, s0b);
      s1b = MFMA32(q[kk + 1], b1b, s1b);
    }

    // softmax numerators (no max subtraction; scores bounded) + P -> LDS (bf16)
    u16* pw = &Pl[w][0];
#pragma unroll
    for (int g = 0; g < 16; ++g) {
      int r = (g & 3) + 8 * (g >> 2) + 4 * hi;
      float p0 = __expf((s0a[g] + s0b[g]) * 0.0625f);
      float p1 = __expf((s1a[g] + s1b[g]) * 0.0625f);
      ell[g] += p0 + p1;
      int col0 = l31, col1 = 32 + l31;
      pw[r * 64 + (((col0 >> 3) ^ (r & 7)) * 8) + (col0 & 7)] = f2bf(p0);
      pw[r * 64 + (((col1 >> 3) ^ (r & 7)) * 8) + (col1 & 7)] = f2bf(p1);
    }

    // Z += P * V : 32q x 256head, kv = 4 x 16
    const u16* vb = &Vl[cur][0];
#pragma unroll
    for (int kk = 0; kk < 4; ++kk) {
      int c16 = kk * 2 + hi;
      bf16x8 pa = *(const bf16x8*)(pw + l31 * 64 + ((c16 ^ (l31 & 7)) * 8));
#pragma unroll
      for (int nt = 0; nt < 8; ++nt) {
        int n = nt * 32 + l31;
        bf16x8 vv = *(const bf16x8*)(vb + n * 64 + ((c16 ^ (n & 7)) * 8));
        zacc[nt] = MFMA32(pa, vv, zacc[nt]);
      }
    }
    __syncthreads();  // implicit vmcnt(0): prefetched tile ready; buffers safe to swap
  }

  // row sums: reduce across the 32 lanes sharing hi
#pragma unroll
  for (int g = 0; g < 16; ++g) {
    float e = ell[g];
#pragma unroll
    for (int m = 1; m < 32; m <<= 1) e += __shfl_xor(e, m, 64);
    ell[g] = e;
  }

  const size_t zbase = (size_t)half * (16384u * 256u) + (size_t)(b * 4096 + q0) * 256;
#pragma unroll
  for (int g = 0; g < 16; ++g) {
    int r = (g & 3) + 8 * (g >> 2) + 4 * hi;
#pragma unroll
    for (int nt = 0; nt < 8; ++nt)
      Zp[zbase + (size_t)r * 256 + nt * 32 + l31] = zacc[nt][g];
  }
  if (l31 == 0) {
#pragma unroll
    for (int g = 0; g < 16; ++g) {
      int r = (g & 3) + 8 * (g >> 2) + 4 * hi;
      Lp[half * 16384 + b * 4096 + q0 + r] = ell[g];
    }
  }
}

// ---------- kernel 5: merge KV halves + normalize -> z bf16 ----------
__global__ __launch_bounds__(256) void merge_k(
    const float* __restrict__ Zp, const float* __restrict__ Lp, u16* __restrict__ zb) {
  const int idx = blockIdx.x * 256 + threadIdx.x;  // 524288 threads, 8 cols each
  const int m = idx >> 5;
  const int c = (idx & 31) * 8;
  const float inv = 1.0f / ((Lp[m] + Lp[16384 + m]) * 64.0f);
  const float4v a0 = *(const float4v*)(Zp + (size_t)m * 256 + c);
  const float4v a1 = *(const float4v*)(Zp + (size_t)m * 256 + c + 4);
  const float4v b0 = *(const float4v*)(Zp + 4194304 + (size_t)m * 256 + c);
  const float4v b1 = *(const float4v*)(Zp + 4194304 + (size_t)m * 256 + c + 4);
  u16x8 o;
#pragma unroll
  for (int j = 0; j < 4; ++j) o[j] = f2bf((a0[j] + b0[j]) * inv);
#pragma unroll
  for (int j = 0; j < 4; ++j) o[4 + j] = f2bf((a1[j] + b1[j]) * inv);
  *(u16x8*)(zb + (size_t)m * 256 + c) = o;
}

// ---------- launch ----------
extern "C" void kernel_launch(void* const* d_in, const int* in_sizes, int n_in,
                              void* d_out, int out_size, void* d_ws, size_t ws_size,
                              hipStream_t stream) {
  const float* x  = (const float*)d_in[0];
  const float* cw = (const float*)d_in[1];
  const float* cb = (const float*)d_in[2];
  const float* tw = (const float*)d_in[3];
  const float* tb = (const float*)d_in[4];
  const float* pw = (const float*)d_in[5];
  const float* pb = (const float*)d_in[6];
  const float* gw = (const float*)d_in[7];
  const float* gb = (const float*)d_in[8];
  const float* fw = (const float*)d_in[9];
  const float* fb = (const float*)d_in[10];

  char* ws = (char*)d_ws;
  // layout (with reuse): total ~64.8 MB
  u16*   tpg  = (u16*)(ws);                   // [16384][768] theta|phi|g   25165824 B
  u16*   gT   = (u16*)(ws + 25165824);        // [4][256][4096]              8388608 B
  u16*   zb   = (u16*)(ws + 25165824);        // reuses gT after flash
  u16*   xb   = (u16*)(ws + 33554432);        // dead after h-gemm
  u16*   hb   = (u16*)(ws + 41943040);        // dead after tpg-gemm
  float* Zp   = (float*)(ws + 33554432);      // [2][16384][256] f32, overlaps xb/hb
  float* Lp   = (float*)(ws + 67108864);      // [2][16384]
  u16*   cwb  = (u16*)(ws + 67239936);
  u16*   wcat = (u16*)(ws + 67371008);        // [768][256]
  u16*   fwb  = (u16*)(ws + 67764224);
  float* bcat = (float*)(ws + 67895296);      // [768]

  convert_k<<<4417, 256, 0, stream>>>(x, cw, tw, pw, gw, fw, tb, pb, gb,
                                      xb, cwb, wcat, fwb, bcat);
  // h = x @ conv_w^T + conv_b
  gemm_bt<0><<<dim3(128, 2), 256, 0, stream>>>(xb, cwb, cb, (void*)hb, nullptr, 256, 256);
  // theta|phi|g = h @ wcat^T + bcat
  gemm_bt<0><<<dim3(128, 6), 256, 0, stream>>>(hb, wcat, bcat, (void*)tpg, nullptr, 256, 768);
  transpose_g_k<<<1024, 256, 0, stream>>>(tpg, gT);
  flash_kernel<<<256, 256, 0, stream>>>(tpg, gT, Zp, Lp);
  merge_k<<<2048, 256, 0, stream>>>(Zp, Lp, zb);
  // out = z @ f_w^T + f_b + x
  gemm_bt<1><<<dim3(128, 2), 256, 0, stream>>>(zb, fwb, fb, d_out, x, 256, 256);
}

// Round 2
// 215.247 us; speedup vs baseline: 1.1655x; 1.1655x over previous
//
#include <hip/hip_runtime.h>

// ---------- types ----------
typedef unsigned short u16;
typedef __bf16 bf16x8 __attribute__((ext_vector_type(8)));
typedef float f32x4 __attribute__((ext_vector_type(4)));
typedef float f32x16 __attribute__((ext_vector_type(16)));
typedef float float4v __attribute__((ext_vector_type(4)));
typedef unsigned short u16x8 __attribute__((ext_vector_type(8)));
typedef unsigned short u16x4 __attribute__((ext_vector_type(4)));

#define MFMA16(a, b, c) __builtin_amdgcn_mfma_f32_16x16x32_bf16(a, b, c, 0, 0, 0)
#define MFMA32(a, b, c) __builtin_amdgcn_mfma_f32_32x32x16_bf16(a, b, c, 0, 0, 0)

__device__ __forceinline__ u16 f2bf(float f) {
  union { float f; unsigned u; } v; v.f = f;
  unsigned r = v.u + 0x7fffu + ((v.u >> 16) & 1u);
  return (u16)(r >> 16);
}

// async global->LDS, 16B per lane; LDS dest must be wave-uniform base + lane*16
__device__ __forceinline__ void gload16(const void* g, void* l) {
  __builtin_amdgcn_global_load_lds(
      (__attribute__((address_space(1))) void*)g,
      (__attribute__((address_space(3))) void*)l, 16, 0, 0);
}

__device__ __forceinline__ unsigned cvtpk(float lo, float hi) {
  unsigned r;
  asm("v_cvt_pk_bf16_f32 %0, %1, %2" : "=v"(r) : "v"(lo), "v"(hi));
  return r;
}
// swap a.lanes[32:63] <-> b.lanes[0:31]
__device__ __forceinline__ void plswap(unsigned& a, unsigned& b) {
  asm volatile("v_permlane32_swap_b32 %0, %1" : "+v"(a), "+v"(b));
}

// ---------- kernel 1: fp32 -> bf16 conversions ----------
__global__ __launch_bounds__(256) void convert_k(
    const float* __restrict__ x, const float* __restrict__ cw,
    const float* __restrict__ tw, const float* __restrict__ pw,
    const float* __restrict__ gw, const float* __restrict__ fw,
    const float* __restrict__ tb, const float* __restrict__ pb,
    const float* __restrict__ gb,
    u16* __restrict__ xb, u16* __restrict__ cwb, u16* __restrict__ wcat,
    u16* __restrict__ fwb, float* __restrict__ bcat) {
  const int idx = blockIdx.x * 256 + threadIdx.x;
  const float* src;
  u16* dst;
  int off;
  if (idx < 1048576)      { src = x;  dst = xb;            off = idx; }
  else if (idx < 1064960) { src = cw; dst = cwb;           off = idx - 1048576; }
  else if (idx < 1081344) { src = tw; dst = wcat;          off = idx - 1064960; }
  else if (idx < 1097728) { src = pw; dst = wcat + 65536;  off = idx - 1081344; }
  else if (idx < 1114112) { src = gw; dst = wcat + 131072; off = idx - 1097728; }
  else if (idx < 1130496) { src = fw; dst = fwb;           off = idx - 1114112; }
  else if (idx < 1130688) {
    int j = (idx - 1130496) * 4;
#pragma unroll
    for (int i = 0; i < 4; ++i) {
      int k = j + i;
      bcat[k] = (k < 256) ? tb[k] : (k < 512) ? pb[k - 256] : gb[k - 512];
    }
    return;
  } else return;
  float4v v = *(const float4v*)(src + (size_t)off * 4);
  u16x4 o;
#pragma unroll
  for (int i = 0; i < 4; ++i) o[i] = f2bf(v[i]);
  *(u16x4*)(dst + (size_t)off * 4) = o;
}

// ---------- kernel 2: generic bf16 GEMM, C[m][n] = sum_k A[m][k]*W[n][k] + bias[n] ----------
template <int OM>
__global__ __launch_bounds__(256) void gemm_bt(
    const u16* __restrict__ A, const u16* __restrict__ W,
    const float* __restrict__ bias, void* __restrict__ Cout,
    const float* __restrict__ res, int K, int ldc) {
  __shared__ u16 As[8192];
  __shared__ u16 Bs[8192];
  const int t = threadIdx.x;
  const int lane = t & 63, w = t >> 6;
  const int brow = blockIdx.x * 128, bcol = blockIdx.y * 128;
  const int wr = (w >> 1) * 64, wc = (w & 1) * 64;
  f32x4 acc[4][4];
#pragma unroll
  for (int i = 0; i < 4; ++i)
#pragma unroll
    for (int j = 0; j < 4; ++j)
#pragma unroll
      for (int r = 0; r < 4; ++r) acc[i][j][r] = 0.0f;

  const int sr = t >> 3, sc8 = (t & 7) * 8;
  const u16* gA = A + (size_t)(brow + sr) * K + sc8;
  const u16* gW = W + (size_t)(bcol + sr) * K + sc8;

  for (int kt = 0; kt < K; kt += 64) {
#pragma unroll
    for (int c = 0; c < 4; ++c) {
      gload16(gA + (size_t)c * 32 * K + kt, &As[c * 2048 + t * 8]);
      gload16(gW + (size_t)c * 32 * K + kt, &Bs[c * 2048 + t * 8]);
    }
    __syncthreads();
#pragma unroll
    for (int kk = 0; kk < 2; ++kk) {
      const int ko = kk * 32 + (lane >> 4) * 8;
      bf16x8 af[4], bfr[4];
#pragma unroll
      for (int i = 0; i < 4; ++i)
        af[i] = *(const bf16x8*)(&As[(wr + i * 16 + (lane & 15)) * 64 + ko]);
#pragma unroll
      for (int j = 0; j < 4; ++j)
        bfr[j] = *(const bf16x8*)(&Bs[(wc + j * 16 + (lane & 15)) * 64 + ko]);
#pragma unroll
      for (int i = 0; i < 4; ++i)
#pragma unroll
        for (int j = 0; j < 4; ++j)
          acc[i][j] = MFMA16(af[i], bfr[j], acc[i][j]);
    }
    __syncthreads();
  }

  const int r0 = (lane >> 4) * 4, c0 = lane & 15;
#pragma unroll
  for (int i = 0; i < 4; ++i)
#pragma unroll
    for (int j = 0; j < 4; ++j) {
      const int col = bcol + wc + j * 16 + c0;
      const float bv = bias[col];
#pragma unroll
      for (int r = 0; r < 4; ++r) {
        const size_t o = (size_t)(brow + wr + i * 16 + r0 + r) * ldc + col;
        if (OM == 0) ((u16*)Cout)[o] = f2bf(acc[i][j][r] + bv);
        else         ((float*)Cout)[o] = acc[i][j][r] + bv + res[o];
      }
    }
}

// ---------- kernel 3: transpose g -> gT[b][k][m] ----------
__global__ __launch_bounds__(256) void transpose_g_k(
    const u16* __restrict__ tpg, u16* __restrict__ gT) {
  __shared__ u16 T[64][65];
  const int t = threadIdx.x;
  const int bm = (blockIdx.x & 63) * 64;
  const int bk = ((blockIdx.x >> 6) & 3) * 64;
  const int b = blockIdx.x >> 8;
  const int r = t >> 3, c8 = (t & 7) * 8;
#pragma unroll
  for (int ch = 0; ch < 2; ++ch) {
    u16x8 v = *(const u16x8*)(tpg + (size_t)(b * 4096 + bm + r + ch * 32) * 768 + 512 + bk + c8);
#pragma unroll
    for (int j = 0; j < 8; ++j) T[r + ch * 32][c8 + j] = v[j];
  }
  __syncthreads();
#pragma unroll
  for (int ch = 0; ch < 2; ++ch) {
    u16x8 o;
#pragma unroll
    for (int j = 0; j < 8; ++j) o[j] = T[c8 + j][r + ch * 32];
    *(u16x8*)(gT + (size_t)(b * 256 + bk + r + ch * 32) * 4096 + bm + c8) = o;
  }
}

// ---------- kernel 4: flash attention v2 ----------
// Swapped QK^T (S^T = K*Q^T) -> P lane-local; in-register softmax via
// cvt_pk_bf16 + permlane32_swap; no P LDS. kv-tile 32 double-buffered
// (64 KiB LDS -> 2 blocks/CU). grid 512 = b(4) x quarter(4) x qtile(32).
__global__ __launch_bounds__(256, 2) void flash2(
    const u16* __restrict__ tpg, const u16* __restrict__ gT,
    u16* __restrict__ Zp, float* __restrict__ Lp) {
  __shared__ u16 Kl[2][32 * 256];  // rows=kv(32), 32 c16-groups, swz c16^row
  __shared__ u16 Vl[2][256 * 32];  // rows=d(256), 4 c16-groups, swz c16^((row>>1)&3)

  const int t = threadIdx.x;
  const int lane = t & 63, w = t >> 6;
  const int l31 = lane & 31, hi = lane >> 5;
  const int bid = blockIdx.x;
  const int b = bid >> 7;
  const int quarter = (bid >> 5) & 3;
  const int qt = bid & 31;
  const int q0 = qt * 128 + w * 32;
  const int kv0 = quarter * 1024;

  // Q fragments (theta): B-operand layout, lane holds q-row = q0+l31
  bf16x8 q[16];
  {
    const u16* qp = tpg + (size_t)(b * 4096 + q0 + l31) * 768 + hi * 8;
#pragma unroll
    for (int ks = 0; ks < 16; ++ks) q[ks] = *(const bf16x8*)(qp + ks * 16);
  }

  f32x16 zacc[8];
#pragma unroll
  for (int i = 0; i < 8; ++i)
#pragma unroll
    for (int j = 0; j < 16; ++j) zacc[i][j] = 0.0f;
  float ell = 0.0f;

  const int ksr = t >> 5, ksc = t & 31;  // K staging coords

  auto stage = [&](int tile, int bi) {
    const size_t krow0 = (size_t)(b * 4096 + kv0 + tile * 32);
#pragma unroll
    for (int ch = 0; ch < 4; ++ch) {
      int r = ch * 8 + ksr;
      gload16(tpg + (krow0 + r) * 768 + 256 + ((ksc ^ r) * 8), &Kl[bi][ch * 2048 + t * 8]);
    }
#pragma unroll
    for (int ch = 0; ch < 4; ++ch) {
      int u = ch * 256 + t;
      int r = u >> 2, c16 = u & 3;
      gload16(gT + (size_t)(b * 256 + r) * 4096 + kv0 + tile * 32 + ((c16 ^ ((r >> 1) & 3)) * 8),
              &Vl[bi][u * 8]);
    }
  };

  stage(0, 0);
  __syncthreads();

  for (int tile = 0; tile < 32; ++tile) {
    const int cur = tile & 1;
    if (tile + 1 < 32) stage(tile + 1, cur ^ 1);

    // S^T = K * Q^T : rows=kv(32), cols=q(32); lane owns q-col l31
    f32x16 s;
#pragma unroll
    for (int j = 0; j < 16; ++j) s[j] = 0.0f;
    const u16* kb = &Kl[cur][0];
#pragma unroll
    for (int ks = 0; ks < 16; ++ks) {
      bf16x8 kf = *(const bf16x8*)(kb + l31 * 256 + (((2 * ks + hi) ^ l31) * 8));
      s = MFMA32(kf, q[ks], s);
    }

    // softmax numerators in-register; build PV A-frags via cvt_pk + permlane
    bf16x8 pa[2];
#pragma unroll
    for (int half = 0; half < 2; ++half) {
      float p[8];
#pragma unroll
      for (int g = 0; g < 8; ++g) {
        p[g] = __builtin_amdgcn_exp2f(s[half * 8 + g] * 0.09016844f);
        ell += p[g];
      }
      unsigned x0 = cvtpk(p[0], p[1]), y0 = cvtpk(p[4], p[5]);
      unsigned x1 = cvtpk(p[2], p[3]), y1 = cvtpk(p[6], p[7]);
      plswap(x0, y0);
      plswap(x1, y1);
      union { unsigned u[4]; bf16x8 v; } cc;
      cc.u[0] = x0; cc.u[1] = x1; cc.u[2] = y0; cc.u[3] = y1;
      pa[half] = cc.v;
    }

    // Z += P * V : q(32) x d(256), kv-depth 32 = 2 k-steps
    const u16* vb = &Vl[cur][0];
#pragma unroll
    for (int ks2 = 0; ks2 < 2; ++ks2) {
#pragma unroll
      for (int nt = 0; nt < 8; ++nt) {
        int row = nt * 32 + l31;
        bf16x8 vv = *(const bf16x8*)(vb + row * 32 + (((2 * ks2 + hi) ^ ((row >> 1) & 3)) * 8));
        zacc[nt] = MFMA32(pa[ks2], vv, zacc[nt]);
      }
    }
    __syncthreads();
  }

  // ell: lane and lane+32 hold complementary kv rows of the same q-col
  ell += __shfl_xor(ell, 32, 64);

  // write bf16 partials: Zp[quarter][b*4096 + q][d]
#pragma unroll
  for (int g = 0; g < 16; ++g) {
    int r = (g & 3) + 8 * (g >> 2) + 4 * hi;
    size_t rowoff = ((size_t)(quarter * 16384 + b * 4096 + q0 + r)) * 256 + l31;
#pragma unroll
    for (int nt = 0; nt < 8; ++nt) Zp[rowoff + nt * 32] = f2bf(zacc[nt][g]);
  }
  if (lane < 32) Lp[quarter * 16384 + b * 4096 + q0 + l31] = ell;
}

// ---------- kernel 5: merge 4 KV-quarter partials + normalize -> z bf16 ----------
__global__ __launch_bounds__(256) void merge2(
    const u16* __restrict__ Zp, const float* __restrict__ Lp, u16* __restrict__ zb) {
  const int idx = blockIdx.x * 256 + threadIdx.x;  // 524288 threads, 8 cols each
  const int m = idx >> 5;
  const int c = (idx & 31) * 8;
  const float l = Lp[m] + Lp[16384 + m] + Lp[32768 + m] + Lp[49152 + m];
  const float inv = 1.0f / (l * 64.0f);
  float acc[8];
#pragma unroll
  for (int j = 0; j < 8; ++j) acc[j] = 0.0f;
#pragma unroll
  for (int qd = 0; qd < 4; ++qd) {
    u16x8 v = *(const u16x8*)(Zp + ((size_t)(qd * 16384) + m) * 256 + c);
#pragma unroll
    for (int j = 0; j < 8; ++j) {
      union { unsigned u; float f; } cv;
      cv.u = ((unsigned)v[j]) << 16;
      acc[j] += cv.f;
    }
  }
  u16x8 o;
#pragma unroll
  for (int j = 0; j < 8; ++j) o[j] = f2bf(acc[j] * inv);
  *(u16x8*)(zb + (size_t)m * 256 + c) = o;
}

// ---------- launch ----------
extern "C" void kernel_launch(void* const* d_in, const int* in_sizes, int n_in,
                              void* d_out, int out_size, void* d_ws, size_t ws_size,
                              hipStream_t stream) {
  const float* x  = (const float*)d_in[0];
  const float* cw = (const float*)d_in[1];
  const float* cb = (const float*)d_in[2];
  const float* tw = (const float*)d_in[3];
  const float* tb = (const float*)d_in[4];
  const float* pw = (const float*)d_in[5];
  const float* pb = (const float*)d_in[6];
  const float* gw = (const float*)d_in[7];
  const float* gb = (const float*)d_in[8];
  const float* fw = (const float*)d_in[9];
  const float* fb = (const float*)d_in[10];

  char* ws = (char*)d_ws;
  // layout (with reuse): peak = 67,898,368 B (same as round 1)
  u16*   tpg  = (u16*)(ws);                   // [16384][768] theta|phi|g   25165824 B
  u16*   gT   = (u16*)(ws + 25165824);        // [4][256][4096]              8388608 B
  u16*   zb   = (u16*)(ws + 25165824);        // reuses gT after flash
  u16*   xb   = (u16*)(ws + 33554432);        // dead after h-gemm
  u16*   hb   = (u16*)(ws + 41943040);        // dead after tpg-gemm
  u16*   Zp   = (u16*)(ws + 33554432);        // [4][16384][256] bf16 partials, 33.5 MB
  u16*   cwb  = (u16*)(ws + 67239936);
  u16*   wcat = (u16*)(ws + 67371008);        // [768][256]
  u16*   fwb  = (u16*)(ws + 67764224);
  float* bcat = (float*)(ws + 67895296);      // [768]
  float* Lp   = (float*)d_out;                // [4][16384] f32 — dead before final gemm

  convert_k<<<4417, 256, 0, stream>>>(x, cw, tw, pw, gw, fw, tb, pb, gb,
                                      xb, cwb, wcat, fwb, bcat);
  // h = x @ conv_w^T + conv_b
  gemm_bt<0><<<dim3(128, 2), 256, 0, stream>>>(xb, cwb, cb, (void*)hb, nullptr, 256, 256);
  // theta|phi|g = h @ wcat^T + bcat
  gemm_bt<0><<<dim3(128, 6), 256, 0, stream>>>(hb, wcat, bcat, (void*)tpg, nullptr, 256, 768);
  transpose_g_k<<<1024, 256, 0, stream>>>(tpg, gT);
  flash2<<<512, 256, 0, stream>>>(tpg, gT, Zp, Lp);
  merge2<<<2048, 256, 0, stream>>>(Zp, Lp, zb);
  // out = z @ f_w^T + f_b + x
  gemm_bt<1><<<dim3(128, 2), 256, 0, stream>>>(zb, fwb, fb, d_out, x, 256, 256);
}